// Round 6
// baseline (422.853 us; speedup 1.0000x reference)
//
#include <hip/hip_runtime.h>
#include <cstdint>
#include <cstddef>

// B=2, S=1024, D=512, NH=16 (chunk width), C=32 chunks.
// weights output (C,B,S,S) fp32 = 256 MiB written once, never re-read (PV fused).
// out_pre scramble: (c,b,m,h) -> [c>>4][(c&15)*64 + (m>>4)][(m&15)*32 + b*16 + h]

// ---------------------------------------------------------------------------
// NT GEMM body: P[M][512] = X[M][512] * W[512][512]^T   (tiles 64x64x32)
// ---------------------------------------------------------------------------
__device__ __forceinline__ void gemm_nt_body(const float* __restrict__ X,
                                             const float* __restrict__ W,
                                             float* __restrict__ P)
{
    __shared__ float As[32][68];
    __shared__ float Bs[32][68];
    const int t  = threadIdx.x;
    const int tx = t & 15, ty = t >> 4;
    const int m0 = blockIdx.y << 6;
    const int n0 = blockIdx.x << 6;
    float acc[4][4] = {};
    for (int k0 = 0; k0 < 512; k0 += 32) {
#pragma unroll
        for (int rep = 0; rep < 2; ++rep) {
            int f  = rep * 256 + t;
            int r  = f >> 3, c4 = f & 7;
            float4 xv = *(const float4*)(X + (size_t)(m0 + r) * 512 + k0 + c4 * 4);
            As[c4 * 4 + 0][r] = xv.x; As[c4 * 4 + 1][r] = xv.y;
            As[c4 * 4 + 2][r] = xv.z; As[c4 * 4 + 3][r] = xv.w;
            float4 wv = *(const float4*)(W + (size_t)(n0 + r) * 512 + k0 + c4 * 4);
            Bs[c4 * 4 + 0][r] = wv.x; Bs[c4 * 4 + 1][r] = wv.y;
            Bs[c4 * 4 + 2][r] = wv.z; Bs[c4 * 4 + 3][r] = wv.w;
        }
        __syncthreads();
#pragma unroll
        for (int kk = 0; kk < 32; ++kk) {
            float4 av = *(const float4*)(&As[kk][ty * 4]);
            float4 bv = *(const float4*)(&Bs[kk][tx * 4]);
            float a[4] = {av.x, av.y, av.z, av.w};
            float b[4] = {bv.x, bv.y, bv.z, bv.w};
#pragma unroll
            for (int i = 0; i < 4; ++i)
#pragma unroll
                for (int j = 0; j < 4; ++j)
                    acc[i][j] += a[i] * b[j];
        }
        __syncthreads();
    }
#pragma unroll
    for (int i = 0; i < 4; ++i) {
        float4 o = make_float4(acc[i][0], acc[i][1], acc[i][2], acc[i][3]);
        *(float4*)(P + (size_t)(m0 + ty * 4 + i) * 512 + n0 + tx * 4) = o;
    }
}

__global__ __launch_bounds__(256, 2) void proj3_kernel(
    const float* __restrict__ Q, const float* __restrict__ K, const float* __restrict__ V,
    const float* __restrict__ Wq, const float* __restrict__ Wk, const float* __restrict__ Wv,
    float* __restrict__ q, float* __restrict__ k, float* __restrict__ v)
{
    const float* X; const float* W; float* P;
    if (blockIdx.z == 0)      { X = Q; W = Wq; P = q; }
    else if (blockIdx.z == 1) { X = K; W = Wk; P = k; }
    else                      { X = V; W = Wv; P = v; }
    gemm_nt_body(X, W, P);
}

__global__ __launch_bounds__(256, 2) void outproj_kernel(
    const float* __restrict__ att, const float* __restrict__ Wo, float* __restrict__ out)
{
    gemm_nt_body(att, Wo, out);
}

// bf16 round-to-nearest-even pack of two positive floats into one u32
__device__ __forceinline__ unsigned pk_bf16(float a, float b) {
    unsigned ua = __float_as_uint(a), ub = __float_as_uint(b);
    ua = (ua + 0x7fffu + ((ua >> 16) & 1u)) >> 16;
    ub = (ub + 0x7fffu + ((ub >> 16) & 1u)) >> 16;
    return ua | (ub << 16);
}
// unpack with scale
__device__ __forceinline__ void upk_bf16(unsigned p, float iv, float& a, float& b) {
    a = __uint_as_float(p << 16) * iv;
    b = __uint_as_float(p & 0xffff0000u) * iv;
}

// ---------------------------------------------------------------------------
// Fused scores + softmax + weights-write + PV.  v5: REALLY fit in 128 VGPRs.
// R2-R5 lesson: 512-thread kernels are hard-capped at 128 VGPRs and the PV
// phase's 64-accumulator butterfly was the spill source. Fix: split PV into
// two h-halves of 32 accumulators each, with its own 5-step+xor32 butterfly
// (R3-verified mapping). Per-phase peak live:
//   scores ~80 (ep packs to 32; q re-read from LDS wave-uniform),
//   weights-store ~60, PV-half ~94 (ep32+ph32+ec16+inv4+addr).
// Block = (c, b, 256-row tile), 512 threads, grid = 256 (1 block/CU).
// LDS: khT[16][1024] + vsT[16][1024] + qs[256][16] = 144 KiB.
// ---------------------------------------------------------------------------
__global__ __launch_bounds__(512, 2)
void attn_fused_kernel(
    const float* __restrict__ q, const float* __restrict__ k, const float* __restrict__ v,
    float* __restrict__ wts, float* __restrict__ att)
{
    __shared__ float khT[16][1024];
    __shared__ float vsT[16][1024];
    __shared__ float qs[256][16];
    const int t   = threadIdx.x;
    const int bid = blockIdx.x;       // 256 blocks
    const int mt  = bid & 3;          // 4 row tiles of 256
    const int cb  = bid >> 2;         // c*2 + b
    const int b   = cb & 1;
    const int c   = cb >> 1;
    const int m0  = mt << 8;

    const float* kb = k + (size_t)b * 524288 + c * 16;
    const float* vb = v + (size_t)b * 524288 + c * 16;
    const float* qb = q + (size_t)b * 524288 + (size_t)m0 * 512 + c * 16;

#pragma unroll
    for (int rep = 0; rep < 8; ++rep) {
        int f = rep * 512 + t;        // 4096 float4-slots
        int n = f >> 2, hq = f & 3;
        float4 kv = *(const float4*)(kb + (size_t)n * 512 + hq * 4);
        khT[hq*4+0][n] = kv.x; khT[hq*4+1][n] = kv.y;
        khT[hq*4+2][n] = kv.z; khT[hq*4+3][n] = kv.w;
        float4 vv = *(const float4*)(vb + (size_t)n * 512 + hq * 4);
        vsT[hq*4+0][n] = vv.x; vsT[hq*4+1][n] = vv.y;
        vsT[hq*4+2][n] = vv.z; vsT[hq*4+3][n] = vv.w;
    }
#pragma unroll
    for (int rep = 0; rep < 2; ++rep) {
        int f = rep * 512 + t;        // 1024 float4-slots
        int r = f >> 2, hq = f & 3;
        *(float4*)(&qs[r][hq*4]) = *(const float4*)(qb + (size_t)r * 512 + hq * 4);
    }
    __syncthreads();

    const int wave = t >> 6, lane = t & 63;
    const int n4   = lane * 4;
    float* wbase = wts + (size_t)cb * 1048576 + (size_t)m0 * 1024;

#pragma unroll 1
    for (int pq = 0; pq < 8; ++pq) {
        const int r0 = wave * 32 + pq * 4;   // row within 256-tile

        // ---- phase 1: scores + exp + bf16-pack (ep[4][8] = 32 regs) ----
        unsigned ep[4][8];
        float sum[4] = {0.f, 0.f, 0.f, 0.f};
#pragma unroll
        for (int i = 0; i < 4; ++i) {
            float s0[4] = {}, s1[4] = {}, s2[4] = {}, s3[4] = {};
#pragma unroll
            for (int hq = 0; hq < 4; ++hq) {
                float4 qv0 = *(const float4*)(&qs[r0 + 0][hq * 4]);
                float4 qv1 = *(const float4*)(&qs[r0 + 1][hq * 4]);
                float4 qv2 = *(const float4*)(&qs[r0 + 2][hq * 4]);
                float4 qv3 = *(const float4*)(&qs[r0 + 3][hq * 4]);
#define SC_STEP(HH, QF0, QF1, QF2, QF3)                                     \
                {                                                           \
                    float4 kv = *(const float4*)(&khT[hq*4+HH][i*256+n4]);  \
                    s0[0] += QF0*kv.x; s0[1] += QF0*kv.y;                   \
                    s0[2] += QF0*kv.z; s0[3] += QF0*kv.w;                   \
                    s1[0] += QF1*kv.x; s1[1] += QF1*kv.y;                   \
                    s1[2] += QF1*kv.z; s1[3] += QF1*kv.w;                   \
                    s2[0] += QF2*kv.x; s2[1] += QF2*kv.y;                   \
                    s2[2] += QF2*kv.z; s2[3] += QF2*kv.w;                   \
                    s3[0] += QF3*kv.x; s3[1] += QF3*kv.y;                   \
                    s3[2] += QF3*kv.z; s3[3] += QF3*kv.w;                   \
                }
                SC_STEP(0, qv0.x, qv1.x, qv2.x, qv3.x)
                SC_STEP(1, qv0.y, qv1.y, qv2.y, qv3.y)
                SC_STEP(2, qv0.z, qv1.z, qv2.z, qv3.z)
                SC_STEP(3, qv0.w, qv1.w, qv2.w, qv3.w)
#undef SC_STEP
            }
#define EXP_PACK(RR, SR)                                                    \
            {                                                               \
                float e0 = __expf(SR[0] * 0.25f);                           \
                float e1 = __expf(SR[1] * 0.25f);                           \
                float e2 = __expf(SR[2] * 0.25f);                           \
                float e3 = __expf(SR[3] * 0.25f);                           \
                sum[RR] += (e0 + e1) + (e2 + e3);                           \
                ep[RR][i*2]   = pk_bf16(e0, e1);                            \
                ep[RR][i*2+1] = pk_bf16(e2, e3);                            \
            }
            EXP_PACK(0, s0) EXP_PACK(1, s1) EXP_PACK(2, s2) EXP_PACK(3, s3)
#undef EXP_PACK
        }
        // ---- phase 2: row-sum allreduce -> inv[4] ----
        float inv[4];
#pragma unroll
        for (int rr = 0; rr < 4; ++rr) {
            float s = sum[rr];
#pragma unroll
            for (int off = 32; off; off >>= 1) s += __shfl_xor(s, off);
            inv[rr] = 1.0f / s;
        }
        // ---- phase 3: coalesced float4 weights store (bf16(e) * inv) ----
#pragma unroll
        for (int rr = 0; rr < 4; ++rr) {
            float* wrow = wbase + (size_t)(r0 + rr) * 1024;
#pragma unroll
            for (int i = 0; i < 4; ++i) {
                float a, bq, cq, d;
                upk_bf16(ep[rr][i*2],   inv[rr], a, bq);
                upk_bf16(ep[rr][i*2+1], inv[rr], cq, d);
                *(float4*)(&wrow[i * 256 + n4]) = make_float4(a, bq, cq, d);
            }
        }
        // ---- phase 4: PV in two h-halves (32 accumulators each) ----
#pragma unroll 1
        for (int H = 0; H < 2; ++H) {
            float ph[32] = {};
#pragma unroll
            for (int i = 0; i < 4; ++i) {
                float ec[4][4];
#pragma unroll
                for (int rr = 0; rr < 4; ++rr) {
                    upk_bf16(ep[rr][i*2],   inv[rr], ec[rr][0], ec[rr][1]);
                    upk_bf16(ep[rr][i*2+1], inv[rr], ec[rr][2], ec[rr][3]);
                }
#pragma unroll
                for (int hh = 0; hh < 8; ++hh) {
                    float4 vv = *(const float4*)(&vsT[H*8+hh][i*256+n4]);
                    ph[0*8+hh] += ec[0][0]*vv.x + ec[0][1]*vv.y
                                + ec[0][2]*vv.z + ec[0][3]*vv.w;
                    ph[1*8+hh] += ec[1][0]*vv.x + ec[1][1]*vv.y
                                + ec[1][2]*vv.z + ec[1][3]*vv.w;
                    ph[2*8+hh] += ec[2][0]*vv.x + ec[2][1]*vv.y
                                + ec[2][2]*vv.z + ec[2][3]*vv.w;
                    ph[3*8+hh] += ec[3][0]*vv.x + ec[3][1]*vv.y
                                + ec[3][2]*vv.z + ec[3][3]*vv.w;
                }
            }
            // 5-step reduce-scatter butterfly over 32 values (R3-verified)
            // + xor-32 completes the 64-lane sum: lane L holds idx L&31.
#pragma unroll
            for (int s = 0; s < 5; ++s) {
                const int msk = 1 << s;
                const int bit = (lane >> s) & 1;
                const int cnt = 32 >> s;
#pragma unroll
                for (int u = 0; u < cnt / 2; ++u) {
                    float a  = ph[2 * u];
                    float bb = ph[2 * u + 1];
                    float keep = bit ? bb : a;
                    float send = bit ? a : bb;
                    ph[u] = keep + __shfl_xor(send, msk);
                }
            }
            ph[0] += __shfl_xor(ph[0], 32);
            // idx = L&31 = rr*8+hh -> row r0+rr, h = H*8+hh
            if (lane < 32) {
                const int rr = lane >> 3;
                const int h  = H * 8 + (lane & 7);
                const int m  = m0 + r0 + rr;
                const int b2 = c >> 4;
                const int m2 = (c & 15) * 64 + (m >> 4);
                const int d2 = (m & 15) * 32 + b * 16 + h;
                att[((size_t)b2 * 1024 + m2) * 512 + d2] = ph[0];
            }
        }
    }
}

// ---------------------------------------------------------------------------
extern "C" void kernel_launch(void* const* d_in, const int* in_sizes, int n_in,
                              void* d_out, int out_size, void* d_ws, size_t ws_size,
                              hipStream_t stream)
{
    (void)in_sizes; (void)n_in; (void)out_size; (void)ws_size;
    const float* Q  = (const float*)d_in[0];
    const float* K  = (const float*)d_in[1];
    const float* V  = (const float*)d_in[2];
    const float* Wq = (const float*)d_in[3];
    const float* Wk = (const float*)d_in[4];
    const float* Wv = (const float*)d_in[5];
    const float* Wo = (const float*)d_in[6];

    float* out = (float*)d_out;
    float* wts = out + 1048576;            // weights output region (64M floats)

    float* ws  = (float*)d_ws;
    float* q   = ws;                        // 1M floats
    float* k   = ws + (1u << 20);           // 1M
    float* v   = ws + 2 * (1u << 20);       // 1M
    float* att = ws + 3 * (1u << 20);       // 1M (scrambled out_pre)

    proj3_kernel<<<dim3(8, 32, 3), 256, 0, stream>>>(Q, K, V, Wq, Wk, Wv, q, k, v);
    attn_fused_kernel<<<256, 512, 0, stream>>>(q, k, v, wts, att);
    outproj_kernel<<<dim3(8, 32, 1), 256, 0, stream>>>(att, Wo, out);
}

// Round 7
// 241.547 us; speedup vs baseline: 1.7506x; 1.7506x over previous
//
#include <hip/hip_runtime.h>
#include <cstdint>
#include <cstddef>

// B=2, S=1024, D=512, NH=16 (chunk width), C=32 chunks.
// weights output (C,B,S,S) fp32 = 256 MiB written once, never re-read (PV fused).
// out_pre scramble: (c,b,m,h) -> [c>>4][(c&15)*64 + (m>>4)][(m&15)*32 + b*16 + h]

// ---------------------------------------------------------------------------
// NT GEMM body: P[M][512] = X[M][512] * W[512][512]^T   (tiles 64x64x32)
// ---------------------------------------------------------------------------
__device__ __forceinline__ void gemm_nt_body(const float* __restrict__ X,
                                             const float* __restrict__ W,
                                             float* __restrict__ P)
{
    __shared__ float As[32][68];
    __shared__ float Bs[32][68];
    const int t  = threadIdx.x;
    const int tx = t & 15, ty = t >> 4;
    const int m0 = blockIdx.y << 6;
    const int n0 = blockIdx.x << 6;
    float acc[4][4] = {};
    for (int k0 = 0; k0 < 512; k0 += 32) {
#pragma unroll
        for (int rep = 0; rep < 2; ++rep) {
            int f  = rep * 256 + t;
            int r  = f >> 3, c4 = f & 7;
            float4 xv = *(const float4*)(X + (size_t)(m0 + r) * 512 + k0 + c4 * 4);
            As[c4 * 4 + 0][r] = xv.x; As[c4 * 4 + 1][r] = xv.y;
            As[c4 * 4 + 2][r] = xv.z; As[c4 * 4 + 3][r] = xv.w;
            float4 wv = *(const float4*)(W + (size_t)(n0 + r) * 512 + k0 + c4 * 4);
            Bs[c4 * 4 + 0][r] = wv.x; Bs[c4 * 4 + 1][r] = wv.y;
            Bs[c4 * 4 + 2][r] = wv.z; Bs[c4 * 4 + 3][r] = wv.w;
        }
        __syncthreads();
#pragma unroll
        for (int kk = 0; kk < 32; ++kk) {
            float4 av = *(const float4*)(&As[kk][ty * 4]);
            float4 bv = *(const float4*)(&Bs[kk][tx * 4]);
            float a[4] = {av.x, av.y, av.z, av.w};
            float b[4] = {bv.x, bv.y, bv.z, bv.w};
#pragma unroll
            for (int i = 0; i < 4; ++i)
#pragma unroll
                for (int j = 0; j < 4; ++j)
                    acc[i][j] += a[i] * b[j];
        }
        __syncthreads();
    }
#pragma unroll
    for (int i = 0; i < 4; ++i) {
        float4 o = make_float4(acc[i][0], acc[i][1], acc[i][2], acc[i][3]);
        *(float4*)(P + (size_t)(m0 + ty * 4 + i) * 512 + n0 + tx * 4) = o;
    }
}

__global__ __launch_bounds__(256, 2) void proj3_kernel(
    const float* __restrict__ Q, const float* __restrict__ K, const float* __restrict__ V,
    const float* __restrict__ Wq, const float* __restrict__ Wk, const float* __restrict__ Wv,
    float* __restrict__ q, float* __restrict__ k, float* __restrict__ v)
{
    const float* X; const float* W; float* P;
    if (blockIdx.z == 0)      { X = Q; W = Wq; P = q; }
    else if (blockIdx.z == 1) { X = K; W = Wk; P = k; }
    else                      { X = V; W = Wv; P = v; }
    gemm_nt_body(X, W, P);
}

__global__ __launch_bounds__(256, 2) void outproj_kernel(
    const float* __restrict__ att, const float* __restrict__ Wo, float* __restrict__ out)
{
    gemm_nt_body(att, Wo, out);
}

// ---------------------------------------------------------------------------
// Fused scores + softmax + weights-write + PV.  v6: 256 threads / 4 waves.
// R2-R6 lesson: 512-thread workgroups are hard-capped at 128 VGPRs (all 8
// waves must co-reside -> 2 waves/SIMD -> compiler pins 128) and every
// restructuring attempt under that cap spilled. 256 threads = 4 waves =
// 1 wave/SIMD minimum; amdgpu_waves_per_eu(1,1) legalizes a 256+ VGPR
// allocation. v3 structure (best measured) now fits: peak live ~150.
//  - fp32 e[4][16] (bf16 packing reverted), inv folded into e once.
//  - R=4 rows/pass, 8 passes/wave, 128 rows/block, 512 blocks.
//  - single 6-step in-place reduce-scatter butterfly (R1/R2-verified).
// LDS: khT[16][1024] + vsT[16][1024] + qs[128][16] = 136 KiB -> 1 block/CU.
// Inner loop is 16 FMA per ds_read_b128 (32 VALU cyc vs ~12 LDS cyc), so
// VALU-bound even at 1 wave/SIMD.
// ---------------------------------------------------------------------------
__global__ __launch_bounds__(256)
__attribute__((amdgpu_waves_per_eu(1, 1)))
void attn_fused_kernel(
    const float* __restrict__ q, const float* __restrict__ k, const float* __restrict__ v,
    float* __restrict__ wts, float* __restrict__ att)
{
    __shared__ float khT[16][1024];
    __shared__ float vsT[16][1024];
    __shared__ float qs[128][16];
    const int t   = threadIdx.x;
    const int bid = blockIdx.x;       // 512 blocks
    const int mt  = bid & 7;          // 8 row tiles of 128
    const int cb  = bid >> 3;         // c*2 + b
    const int b   = cb & 1;
    const int c   = cb >> 1;
    const int m0  = mt << 7;

    const float* kb = k + (size_t)b * 524288 + c * 16;
    const float* vb = v + (size_t)b * 524288 + c * 16;
    const float* qb = q + (size_t)b * 524288 + (size_t)m0 * 512 + c * 16;

#pragma unroll
    for (int rep = 0; rep < 16; ++rep) {
        int f = rep * 256 + t;        // 4096 float4-slots
        int n = f >> 2, hq = f & 3;
        float4 kv = *(const float4*)(kb + (size_t)n * 512 + hq * 4);
        khT[hq*4+0][n] = kv.x; khT[hq*4+1][n] = kv.y;
        khT[hq*4+2][n] = kv.z; khT[hq*4+3][n] = kv.w;
        float4 vv = *(const float4*)(vb + (size_t)n * 512 + hq * 4);
        vsT[hq*4+0][n] = vv.x; vsT[hq*4+1][n] = vv.y;
        vsT[hq*4+2][n] = vv.z; vsT[hq*4+3][n] = vv.w;
    }
#pragma unroll
    for (int rep = 0; rep < 2; ++rep) {
        int f = rep * 256 + t;        // 512 float4-slots
        int r = f >> 2, hq = f & 3;
        *(float4*)(&qs[r][hq*4]) = *(const float4*)(qb + (size_t)r * 512 + hq * 4);
    }
    __syncthreads();

    const int wave = t >> 6, lane = t & 63;
    const int n4   = lane * 4;
    float* wbase = wts + (size_t)cb * 1048576 + (size_t)m0 * 1024;

#pragma unroll 1
    for (int pq = 0; pq < 8; ++pq) {
        const int r0 = wave * 32 + pq * 4;   // row within 128-tile

        // ---- scores + exp (fp32 e in regs) ----
        float e[4][16];
        float sum[4] = {0.f, 0.f, 0.f, 0.f};
#pragma unroll
        for (int i = 0; i < 4; ++i) {
            float s0[4] = {}, s1[4] = {}, s2[4] = {}, s3[4] = {};
#pragma unroll
            for (int hq = 0; hq < 4; ++hq) {
                float4 qv0 = *(const float4*)(&qs[r0 + 0][hq * 4]);
                float4 qv1 = *(const float4*)(&qs[r0 + 1][hq * 4]);
                float4 qv2 = *(const float4*)(&qs[r0 + 2][hq * 4]);
                float4 qv3 = *(const float4*)(&qs[r0 + 3][hq * 4]);
#define SC_STEP(HH, QF0, QF1, QF2, QF3)                                     \
                {                                                           \
                    float4 kv = *(const float4*)(&khT[hq*4+HH][i*256+n4]);  \
                    s0[0] += QF0*kv.x; s0[1] += QF0*kv.y;                   \
                    s0[2] += QF0*kv.z; s0[3] += QF0*kv.w;                   \
                    s1[0] += QF1*kv.x; s1[1] += QF1*kv.y;                   \
                    s1[2] += QF1*kv.z; s1[3] += QF1*kv.w;                   \
                    s2[0] += QF2*kv.x; s2[1] += QF2*kv.y;                   \
                    s2[2] += QF2*kv.z; s2[3] += QF2*kv.w;                   \
                    s3[0] += QF3*kv.x; s3[1] += QF3*kv.y;                   \
                    s3[2] += QF3*kv.z; s3[3] += QF3*kv.w;                   \
                }
                SC_STEP(0, qv0.x, qv1.x, qv2.x, qv3.x)
                SC_STEP(1, qv0.y, qv1.y, qv2.y, qv3.y)
                SC_STEP(2, qv0.z, qv1.z, qv2.z, qv3.z)
                SC_STEP(3, qv0.w, qv1.w, qv2.w, qv3.w)
#undef SC_STEP
            }
#pragma unroll
            for (int j = 0; j < 4; ++j) {
                e[0][i*4+j] = __expf(s0[j] * 0.25f); sum[0] += e[0][i*4+j];
                e[1][i*4+j] = __expf(s1[j] * 0.25f); sum[1] += e[1][i*4+j];
                e[2][i*4+j] = __expf(s2[j] * 0.25f); sum[2] += e[2][i*4+j];
                e[3][i*4+j] = __expf(s3[j] * 0.25f); sum[3] += e[3][i*4+j];
            }
        }
        // ---- row-sum allreduce -> fold inv into e ----
#pragma unroll
        for (int rr = 0; rr < 4; ++rr) {
            float s = sum[rr];
#pragma unroll
            for (int off = 32; off; off >>= 1) s += __shfl_xor(s, off);
            float iv = 1.0f / s;
#pragma unroll
            for (int x = 0; x < 16; ++x) e[rr][x] *= iv;
        }
        // ---- coalesced float4 weights store ----
#pragma unroll
        for (int rr = 0; rr < 4; ++rr) {
            float* wrow = wbase + (size_t)(r0 + rr) * 1024;
#pragma unroll
            for (int i = 0; i < 4; ++i)
                *(float4*)(&wrow[i * 256 + n4]) =
                    make_float4(e[rr][i*4+0], e[rr][i*4+1], e[rr][i*4+2], e[rr][i*4+3]);
        }
        // ---- PV partials ----
        float part[64] = {};
#pragma unroll
        for (int i = 0; i < 4; ++i) {
#pragma unroll
            for (int h = 0; h < 16; ++h) {
                float4 vv = *(const float4*)(&vsT[h][i * 256 + n4]);
                part[0*16+h] += e[0][i*4+0]*vv.x + e[0][i*4+1]*vv.y
                              + e[0][i*4+2]*vv.z + e[0][i*4+3]*vv.w;
                part[1*16+h] += e[1][i*4+0]*vv.x + e[1][i*4+1]*vv.y
                              + e[1][i*4+2]*vv.z + e[1][i*4+3]*vv.w;
                part[2*16+h] += e[2][i*4+0]*vv.x + e[2][i*4+1]*vv.y
                              + e[2][i*4+2]*vv.z + e[2][i*4+3]*vv.w;
                part[3*16+h] += e[3][i*4+0]*vv.x + e[3][i*4+1]*vv.y
                              + e[3][i*4+2]*vv.z + e[3][i*4+3]*vv.w;
            }
        }
        // ---- 6-step reduce-scatter butterfly IN PLACE on part[64] ----
        // lane L ends holding the all-lane sum of original part[L], L = rr*16+h
#pragma unroll
        for (int s = 0; s < 6; ++s) {
            const int msk = 1 << s;
            const int bit = (lane >> s) & 1;
            const int cnt = 64 >> s;
#pragma unroll
            for (int u = 0; u < cnt / 2; ++u) {
                float a  = part[2 * u];
                float bb = part[2 * u + 1];
                float keep = bit ? bb : a;
                float send = bit ? a : bb;
                part[u] = keep + __shfl_xor(send, msk);
            }
        }
        // ---- scrambled att write: one float per lane ----
        const int m  = m0 + r0 + (lane >> 4);
        const int h  = lane & 15;
        const int b2 = c >> 4;
        const int m2 = (c & 15) * 64 + (m >> 4);
        const int d2 = (m & 15) * 32 + b * 16 + h;
        att[((size_t)b2 * 1024 + m2) * 512 + d2] = part[0];
    }
}

// ---------------------------------------------------------------------------
extern "C" void kernel_launch(void* const* d_in, const int* in_sizes, int n_in,
                              void* d_out, int out_size, void* d_ws, size_t ws_size,
                              hipStream_t stream)
{
    (void)in_sizes; (void)n_in; (void)out_size; (void)ws_size;
    const float* Q  = (const float*)d_in[0];
    const float* K  = (const float*)d_in[1];
    const float* V  = (const float*)d_in[2];
    const float* Wq = (const float*)d_in[3];
    const float* Wk = (const float*)d_in[4];
    const float* Wv = (const float*)d_in[5];
    const float* Wo = (const float*)d_in[6];

    float* out = (float*)d_out;
    float* wts = out + 1048576;            // weights output region (64M floats)

    float* ws  = (float*)d_ws;
    float* q   = ws;                        // 1M floats
    float* k   = ws + (1u << 20);           // 1M
    float* v   = ws + 2 * (1u << 20);       // 1M
    float* att = ws + 3 * (1u << 20);       // 1M (scrambled out_pre)

    proj3_kernel<<<dim3(8, 32, 3), 256, 0, stream>>>(Q, K, V, Wq, Wk, Wv, q, k, v);
    attn_fused_kernel<<<512, 256, 0, stream>>>(q, k, v, wts, att);
    outproj_kernel<<<dim3(8, 32, 1), 256, 0, stream>>>(att, Wo, out);
}